// Round 7
// baseline (83.873 us; speedup 1.0000x reference)
//
#include <hip/hip_runtime.h>

// Block Hadamard (block=128) = natural-order FWHT * 1/sqrt(128).
// v8 = v7 (coalesced, 16 elems/lane, DPP fine stages, sign-FMA, NT stores)
//      + contiguous-span scheduling: each wave owns 8 consecutive 4KB chunks
//      (32 KB sequential run) instead of grid-striding 32 MB between chunks.
//      8192 waves x 32 KB = 256 MiB exactly. Longer sequential runs per
//      address stream -> better HBM row-buffer locality.

typedef float f32x4 __attribute__((ext_vector_type(4)));

__device__ __forceinline__ float dpp_xor1(float v) {
    int i = __float_as_int(v);
    int r = __builtin_amdgcn_update_dpp(i, i, 0xB1, 0xF, 0xF, true);
    return __int_as_float(r);
}
__device__ __forceinline__ float dpp_xor2(float v) {
    int i = __float_as_int(v);
    int r = __builtin_amdgcn_update_dpp(i, i, 0x4E, 0xF, 0xF, true);
    return __int_as_float(r);
}

__global__ __launch_bounds__(256) void BlockHadamardTransform_88957362634992_kernel(
    const f32x4* __restrict__ x, f32x4* __restrict__ y, int spans_per_wave) {
    const float scale = 0.08838834764831845f;  // 1/sqrt(128)
    const int t = blockIdx.x * blockDim.x + threadIdx.x;
    const int w = t >> 6;
    const int lane = t & 63;
    const float s1 = (lane & 1) ? -1.f : 1.f;
    const float s2 = (lane & 2) ? -1.f : 1.f;
    const float s4 = (lane & 4) ? -1.f : 1.f;
    const float s8 = (lane & 8) ? -1.f : 1.f;
    const float s16 = (lane & 16) ? -1.f : 1.f;
    for (int it = 0; it < spans_per_wave; ++it) {
        const size_t c = (size_t)w * spans_per_wave + it;  // contiguous chunks per wave
        const size_t base = c * 256 + lane;
        float r[16];
        #pragma unroll
        for (int k = 0; k < 4; ++k) {
            f32x4 v = x[base + 64 * k];
            r[4 * k + 0] = v.x;
            r[4 * k + 1] = v.y;
            r[4 * k + 2] = v.z;
            r[4 * k + 3] = v.w;
        }
        // stages h=1,2 : within each float4
        #pragma unroll
        for (int k = 0; k < 4; ++k) {
            float a0 = r[4 * k + 0] + r[4 * k + 1];
            float a1 = r[4 * k + 0] - r[4 * k + 1];
            float a2 = r[4 * k + 2] + r[4 * k + 3];
            float a3 = r[4 * k + 2] - r[4 * k + 3];
            r[4 * k + 0] = a0 + a2;
            r[4 * k + 1] = a1 + a3;
            r[4 * k + 2] = a0 - a2;
            r[4 * k + 3] = a1 - a3;
        }
        // h=4 : lane^1 via DPP (VALU pipe)
        #pragma unroll
        for (int i = 0; i < 16; ++i) {
            float p = dpp_xor1(r[i]);
            r[i] = fmaf(s1, r[i], p);
        }
        // h=8 : lane^2 via DPP (VALU pipe)
        #pragma unroll
        for (int i = 0; i < 16; ++i) {
            float p = dpp_xor2(r[i]);
            r[i] = fmaf(s2, r[i], p);
        }
        // h=16,32,64 : lane^{4,8,16} via shfl (DS pipe)
        #pragma unroll
        for (int i = 0; i < 16; ++i) {
            float p = __shfl_xor(r[i], 4);
            r[i] = fmaf(s4, r[i], p);
        }
        #pragma unroll
        for (int i = 0; i < 16; ++i) {
            float p = __shfl_xor(r[i], 8);
            r[i] = fmaf(s8, r[i], p);
        }
        #pragma unroll
        for (int i = 0; i < 16; ++i) {
            float p = __shfl_xor(r[i], 16);
            r[i] = fmaf(s16, r[i], p);
        }
        #pragma unroll
        for (int k = 0; k < 4; ++k) {
            f32x4 o;
            o.x = r[4 * k + 0] * scale;
            o.y = r[4 * k + 1] * scale;
            o.z = r[4 * k + 2] * scale;
            o.w = r[4 * k + 3] * scale;
            __builtin_nontemporal_store(o, &y[base + 64 * k]);
        }
    }
}

extern "C" void kernel_launch(void* const* d_in, const int* in_sizes, int n_in,
                              void* d_out, int out_size, void* d_ws, size_t ws_size,
                              hipStream_t stream) {
    const f32x4* x = (const f32x4*)d_in[0];
    f32x4* y = (f32x4*)d_out;
    const int threads = 256;
    const int blocks = 2048;                       // 8192 waves, 32 waves/CU
    const int nchunks = out_size / 1024;           // 65536 chunks of 4 KB
    const int spans_per_wave = nchunks / 8192;     // 8 -> 32 KB contiguous per wave
    BlockHadamardTransform_88957362634992_kernel<<<blocks, threads, 0, stream>>>(x, y, spans_per_wave);
}